// Round 1
// baseline (206.122 us; speedup 1.0000x reference)
//
#include <hip/hip_runtime.h>
#include <hip/hip_bf16.h>
#include <math.h>

#define E_EDGES 1000000
#define N_NODES 50000
#define N_C     64
#define N_REL   8
#define NCOL    512   // N_REL * N_C

typedef __attribute__((ext_vector_type(8))) short  short8;
typedef __attribute__((ext_vector_type(4))) float  floatx4;

// round-to-nearest-even fp32 -> bf16 bits
static __device__ __forceinline__ unsigned short f2bf(float x) {
    union { float f; unsigned int u; } v; v.f = x;
    unsigned int u = v.u;
    unsigned int r = (u + 0x7fffu + ((u >> 16) & 1u)) >> 16;
    return (unsigned short)r;
}

// Kernel 1: compute W (sigmoid * hard-concrete gate) -> bf16 [512][64],
// convert assignments fp32 -> bf16 [50000][64], zero d_out.
__global__ __launch_bounds__(256) void prep_kernel(
    const float* __restrict__ assign,
    const float* __restrict__ icl,
    const float* __restrict__ la,
    unsigned short* __restrict__ Wbf,
    unsigned short* __restrict__ Abf,
    float* __restrict__ out)
{
    int tid = blockIdx.x * blockDim.x + threadIdx.x;
    int nth = gridDim.x * blockDim.x;
    if (tid == 0) out[0] = 0.0f;

    for (int i = tid; i < N_REL * N_C * N_C; i += nth) {
        float w = 1.0f / (1.0f + __expf(-icl[i]));
        float g = 1.0f / (1.0f + __expf(-la[i])) * 1.2f - 0.1f;
        g = fminf(fmaxf(g, 0.0f), 1.0f);
        Wbf[i] = f2bf(w * g);
    }

    const float4* a4 = (const float4*)assign;
    ushort4* o4 = (ushort4*)Abf;
    int n4 = N_NODES * N_C / 4;
    for (int i = tid; i < n4; i += nth) {
        float4 v = a4[i];
        ushort4 o;
        o.x = f2bf(v.x); o.y = f2bf(v.y); o.z = f2bf(v.z); o.w = f2bf(v.w);
        o4[i] = o;
    }
}

// Kernel 2: Y[n][r*64+i] = sum_k A[n][k] * W_r[i][k]  (bf16 MFMA GEMM)
// One wave per 16-row M-tile; loops 32 N-tiles; K=64 = 2 MFMA steps.
__global__ __launch_bounds__(256) void ygemm_kernel(
    const unsigned short* __restrict__ Abf,
    const unsigned short* __restrict__ Wbf,   // [512][64] row-major = Bt[col][k]
    unsigned short* __restrict__ Y)
{
    int wave = (blockIdx.x * blockDim.x + threadIdx.x) >> 6;
    int lane = threadIdx.x & 63;
    if (wave >= N_NODES / 16) return;
    int r16 = lane & 15, quad = lane >> 4;

    // A-operand frags: A[m = lane&15][k = quad*8 + j], two k-steps
    const unsigned short* arow = Abf + (wave * 16 + r16) * N_C + quad * 8;
    short8 a0 = *(const short8*)(arow);
    short8 a1 = *(const short8*)(arow + 32);

    for (int nt = 0; nt < 32; ++nt) {
        int col = nt * 16 + r16;
        const unsigned short* brow = Wbf + col * N_C + quad * 8;
        short8 b0 = *(const short8*)(brow);
        short8 b1 = *(const short8*)(brow + 32);
        floatx4 acc = {0.0f, 0.0f, 0.0f, 0.0f};
        acc = __builtin_amdgcn_mfma_f32_16x16x32_bf16(a0, b0, acc, 0, 0, 0);
        acc = __builtin_amdgcn_mfma_f32_16x16x32_bf16(a1, b1, acc, 0, 0, 0);
        // C/D: col = lane&15, row = quad*4 + reg
        #pragma unroll
        for (int reg = 0; reg < 4; ++reg) {
            int m = wave * 16 + quad * 4 + reg;
            Y[m * NCOL + nt * 16 + r16] = f2bf(acc[reg]);
        }
    }
}

// Kernel 3: per-edge dot(assign[src], Y[dst, r]) -> softplus -> reduce.
// 8 lanes per edge, 16B bf16 loads per lane, shuffle-reduce within 8 lanes.
__global__ __launch_bounds__(256) void edge_kernel(
    const unsigned short* __restrict__ Abf,
    const unsigned short* __restrict__ Y,
    const float* __restrict__ absent_bias,
    const int* __restrict__ ei, const int* __restrict__ et,
    const int* __restrict__ nei, const int* __restrict__ net,
    float* __restrict__ out)
{
    int tid = blockIdx.x * blockDim.x + threadIdx.x;
    int l = tid & 7;
    int group = tid >> 3;
    int ngroups = (gridDim.x * blockDim.x) >> 3;
    float acc = 0.0f;

    for (int slot = group; slot < 2 * E_EDGES; slot += ngroups) {
        bool pos = slot < E_EDGES;
        int e = pos ? slot : slot - E_EDGES;
        const int* eidx = pos ? ei : nei;
        const int* etyp = pos ? et : net;
        int s = eidx[e];
        int d = eidx[E_EDGES + e];
        int r = etyp[e];

        uint4 av = *(const uint4*)(Abf + s * N_C + l * 8);
        uint4 yv = *(const uint4*)(Y + d * NCOL + r * N_C + l * 8);

        float dot = 0.0f;
        unsigned int aw[4] = {av.x, av.y, av.z, av.w};
        unsigned int yw[4] = {yv.x, yv.y, yv.z, yv.w};
        #pragma unroll
        for (int j = 0; j < 4; ++j) {
            float alo = __uint_as_float(aw[j] << 16);
            float ahi = __uint_as_float(aw[j] & 0xffff0000u);
            float ylo = __uint_as_float(yw[j] << 16);
            float yhi = __uint_as_float(yw[j] & 0xffff0000u);
            dot = fmaf(alo, ylo, dot);
            dot = fmaf(ahi, yhi, dot);
        }
        dot += __shfl_xor(dot, 1);
        dot += __shfl_xor(dot, 2);
        dot += __shfl_xor(dot, 4);

        if (l == 0) {
            float logit = dot + absent_bias[r];
            float x = pos ? -logit : logit;
            // softplus(x) = max(x,0) + log1p(exp(-|x|))
            acc += fmaxf(x, 0.0f) + log1pf(__expf(-fabsf(x)));
        }
    }

    __shared__ float red[256];
    red[threadIdx.x] = acc;
    __syncthreads();
    for (int off = 128; off > 0; off >>= 1) {
        if (threadIdx.x < off) red[threadIdx.x] += red[threadIdx.x + off];
        __syncthreads();
    }
    if (threadIdx.x == 0) atomicAdd(out, red[0] * (1.0f / (float)E_EDGES));
}

extern "C" void kernel_launch(void* const* d_in, const int* in_sizes, int n_in,
                              void* d_out, int out_size, void* d_ws, size_t ws_size,
                              hipStream_t stream) {
    const float* assign = (const float*)d_in[0];
    const float* icl    = (const float*)d_in[1];
    const float* la     = (const float*)d_in[2];
    const float* ab     = (const float*)d_in[3];
    const int*   ei     = (const int*)d_in[4];
    const int*   et     = (const int*)d_in[5];
    const int*   nei    = (const int*)d_in[6];
    const int*   net    = (const int*)d_in[7];
    float* out = (float*)d_out;

    // workspace: Wbf 64KB | Abf 6.4MB | Y 51.2MB  (~57.7MB total)
    unsigned short* Wbf = (unsigned short*)d_ws;
    unsigned short* Abf = (unsigned short*)((char*)d_ws + 65536);
    unsigned short* Y   = (unsigned short*)((char*)d_ws + 65536 + N_NODES * N_C * 2);

    prep_kernel<<<1024, 256, 0, stream>>>(assign, icl, la, Wbf, Abf, out);
    ygemm_kernel<<<(N_NODES / 16 + 3) / 4, 256, 0, stream>>>(Abf, Wbf, Y);
    edge_kernel<<<2048, 256, 0, stream>>>(Abf, Y, ab, ei, et, nei, net, out);
}

// Round 2
// 194.179 us; speedup vs baseline: 1.0615x; 1.0615x over previous
//
#include <hip/hip_runtime.h>
#include <hip/hip_bf16.h>
#include <math.h>

#define E_EDGES 1000000
#define N_NODES 50000
#define N_C     64
#define N_REL   8
#define NCOL    512   // N_REL * N_C

typedef _Float16 half2v __attribute__((ext_vector_type(2)));
typedef _Float16 half8  __attribute__((ext_vector_type(8)));
typedef __attribute__((ext_vector_type(4))) float floatx4;

static __device__ __forceinline__ unsigned short f2h_bits(float x) {
    _Float16 h = (_Float16)x;
    return __builtin_bit_cast(unsigned short, h);
}

// v_dot2_f32_f16: c += a0*b0 + a1*b1 (fp32 accumulate)
static __device__ __forceinline__ float dot2(unsigned a, unsigned y, float c) {
    union U { unsigned u; half2v h; };
    U ua; ua.u = a;
    U uy; uy.u = y;
    return __builtin_amdgcn_fdot2(ua.h, uy.h, c, false);
}

// Kernel 1: W = sigmoid(icl) * hard-concrete gate -> f16 [512][64];
// assignments fp32 -> f16 [50000][64]; zero d_out.
__global__ __launch_bounds__(256) void prep_kernel(
    const float* __restrict__ assign,
    const float* __restrict__ icl,
    const float* __restrict__ la,
    unsigned short* __restrict__ Wh,
    unsigned short* __restrict__ Ah,
    float* __restrict__ out)
{
    int tid = blockIdx.x * blockDim.x + threadIdx.x;
    int nth = gridDim.x * blockDim.x;
    if (tid == 0) out[0] = 0.0f;

    for (int i = tid; i < N_REL * N_C * N_C; i += nth) {
        float w = 1.0f / (1.0f + __expf(-icl[i]));
        float g = 1.0f / (1.0f + __expf(-la[i])) * 1.2f - 0.1f;
        g = fminf(fmaxf(g, 0.0f), 1.0f);
        Wh[i] = f2h_bits(w * g);
    }

    const float4* a4 = (const float4*)assign;
    ushort4* o4 = (ushort4*)Ah;
    int n4 = N_NODES * N_C / 4;
    for (int i = tid; i < n4; i += nth) {
        float4 v = a4[i];
        ushort4 o;
        o.x = f2h_bits(v.x); o.y = f2h_bits(v.y);
        o.z = f2h_bits(v.z); o.w = f2h_bits(v.w);
        o4[i] = o;
    }
}

// Kernel 2: Y[n][r*64+i] = sum_k A[n][k] * W_r[i][k]  (f16 MFMA GEMM).
// One wave per 16 node-rows. Epilogue repacks through LDS (stride 136 halves
// to break bank aliasing) so Y is written as coalesced 16B stores.
__global__ __launch_bounds__(256) void ygemm_kernel(
    const unsigned short* __restrict__ A,
    const unsigned short* __restrict__ W,   // [512][64] row-major
    unsigned short* __restrict__ Y)
{
    __shared__ __align__(16) unsigned short lds[4][16 * 136];
    int wid  = threadIdx.x >> 6;
    int wave = blockIdx.x * 4 + wid;
    int lane = threadIdx.x & 63;
    if (wave >= N_NODES / 16) return;   // no __syncthreads in this kernel
    int r16 = lane & 15, quad = lane >> 4;

    // A-frag: A[m = lane&15][k = quad*8 + j], two K=32 steps
    const unsigned short* arow = A + (wave * 16 + r16) * N_C + quad * 8;
    half8 a0 = *(const half8*)(arow);
    half8 a1 = *(const half8*)(arow + 32);
    unsigned short* myl = lds[wid];

    for (int c = 0; c < 4; ++c) {        // 4 chunks of 128 cols
        #pragma unroll
        for (int t = 0; t < 8; ++t) {
            int col = (c * 8 + t) * 16 + r16;
            const unsigned short* brow = W + col * N_C + quad * 8;
            half8 b0 = *(const half8*)(brow);
            half8 b1 = *(const half8*)(brow + 32);
            floatx4 acc = {0.0f, 0.0f, 0.0f, 0.0f};
            acc = __builtin_amdgcn_mfma_f32_16x16x32_f16(a0, b0, acc, 0, 0, 0);
            acc = __builtin_amdgcn_mfma_f32_16x16x32_f16(a1, b1, acc, 0, 0, 0);
            // C/D: col = lane&15, row = quad*4 + reg
            #pragma unroll
            for (int reg = 0; reg < 4; ++reg) {
                int row = quad * 4 + reg;
                myl[row * 136 + t * 16 + r16] = f2h_bits(acc[reg]);
            }
        }
        __asm__ volatile("s_waitcnt lgkmcnt(0)" ::: "memory");
        // coalesced copy: 16 rows x 128 cols f16 -> Y, 16B per lane per unit
        #pragma unroll
        for (int u = 0; u < 4; ++u) {
            int unit = u * 64 + lane;        // 0..255
            int row = unit >> 4, off = unit & 15;
            uint4 v = *(const uint4*)(myl + row * 136 + off * 8);
            *(uint4*)(Y + (wave * 16 + row) * NCOL + c * 128 + off * 8) = v;
        }
        __asm__ volatile("s_waitcnt lgkmcnt(0)" ::: "memory");
    }
}

// Per-edge loop body: 4 lanes/edge, 2x16B f16 loads per lane, v_dot2 MACs.
static __device__ __forceinline__ float edge_loop(
    const unsigned short* __restrict__ A,
    const unsigned short* __restrict__ Y,
    const float* bias_s,
    const int* __restrict__ eidx, const int* __restrict__ etyp,
    float sign, int group, int ngroups, int l)
{
    float acc = 0.0f;
    for (int e = group; e < E_EDGES; e += ngroups) {
        int s = eidx[e];
        int d = eidx[E_EDGES + e];
        int r = etyp[e];
        const uint4* ap = (const uint4*)(A + s * N_C + l * 16);
        const uint4* yp = (const uint4*)(Y + d * NCOL + r * N_C + l * 16);
        uint4 a0 = ap[0], a1 = ap[1];
        uint4 y0 = yp[0], y1 = yp[1];
        float d0 = 0.0f, d1 = 0.0f;
        d0 = dot2(a0.x, y0.x, d0); d1 = dot2(a1.x, y1.x, d1);
        d0 = dot2(a0.y, y0.y, d0); d1 = dot2(a1.y, y1.y, d1);
        d0 = dot2(a0.z, y0.z, d0); d1 = dot2(a1.z, y1.z, d1);
        d0 = dot2(a0.w, y0.w, d0); d1 = dot2(a1.w, y1.w, d1);
        float dot = d0 + d1;
        dot += __shfl_xor(dot, 1);
        dot += __shfl_xor(dot, 2);
        if (l == 0) {
            float x = sign * (dot + bias_s[r]);
            acc += fmaxf(x, 0.0f) + __logf(1.0f + __expf(-fabsf(x)));
        }
    }
    return acc;
}

__global__ __launch_bounds__(256) void edge_kernel(
    const unsigned short* __restrict__ A,
    const unsigned short* __restrict__ Y,
    const float* __restrict__ absent_bias,
    const int* __restrict__ ei, const int* __restrict__ et,
    const int* __restrict__ nei, const int* __restrict__ net,
    float* __restrict__ out)
{
    __shared__ float bias_s[N_REL];
    if (threadIdx.x < N_REL) bias_s[threadIdx.x] = absent_bias[threadIdx.x];
    __syncthreads();

    int tid = blockIdx.x * blockDim.x + threadIdx.x;
    int l = tid & 3;
    int group = tid >> 2;
    int ngroups = (gridDim.x * blockDim.x) >> 2;

    float acc = 0.0f;
    acc += edge_loop(A, Y, bias_s, ei,  et,  -1.0f, group, ngroups, l);  // pos
    acc += edge_loop(A, Y, bias_s, nei, net,  1.0f, group, ngroups, l);  // neg

    // wave reduce then block reduce
    acc += __shfl_xor(acc, 1);
    acc += __shfl_xor(acc, 2);
    acc += __shfl_xor(acc, 4);
    acc += __shfl_xor(acc, 8);
    acc += __shfl_xor(acc, 16);
    acc += __shfl_xor(acc, 32);
    __shared__ float red[4];
    if ((threadIdx.x & 63) == 0) red[threadIdx.x >> 6] = acc;
    __syncthreads();
    if (threadIdx.x == 0)
        atomicAdd(out, (red[0] + red[1] + red[2] + red[3]) * (1.0f / (float)E_EDGES));
}

extern "C" void kernel_launch(void* const* d_in, const int* in_sizes, int n_in,
                              void* d_out, int out_size, void* d_ws, size_t ws_size,
                              hipStream_t stream) {
    const float* assign = (const float*)d_in[0];
    const float* icl    = (const float*)d_in[1];
    const float* la     = (const float*)d_in[2];
    const float* ab     = (const float*)d_in[3];
    const int*   ei     = (const int*)d_in[4];
    const int*   et     = (const int*)d_in[5];
    const int*   nei    = (const int*)d_in[6];
    const int*   net    = (const int*)d_in[7];
    float* out = (float*)d_out;

    // workspace: Wh 64KB | Ah 6.4MB | Y 51.2MB
    unsigned short* Wh = (unsigned short*)d_ws;
    unsigned short* Ah = (unsigned short*)((char*)d_ws + 65536);
    unsigned short* Y  = (unsigned short*)((char*)d_ws + 65536 + N_NODES * N_C * 2);

    prep_kernel<<<1024, 256, 0, stream>>>(assign, icl, la, Wh, Ah, out);
    ygemm_kernel<<<(N_NODES / 16 + 3) / 4, 256, 0, stream>>>(Ah, Wh, Y);
    edge_kernel<<<2048, 256, 0, stream>>>(Ah, Y, ab, ei, et, nei, net, out);
}

// Round 3
// 192.833 us; speedup vs baseline: 1.0689x; 1.0070x over previous
//
#include <hip/hip_runtime.h>
#include <hip/hip_bf16.h>
#include <math.h>

#define E_EDGES 1000000
#define N_NODES 50000
#define N_C     64
#define N_REL   8
#define NCOL    512     // N_REL * N_C
#define GROUPS  250000  // 4 lanes/group, 4 pos + 4 neg edges per group

typedef _Float16 half2v __attribute__((ext_vector_type(2)));
typedef _Float16 half8  __attribute__((ext_vector_type(8)));
typedef __attribute__((ext_vector_type(4))) float floatx4;

static __device__ __forceinline__ unsigned short f2h_bits(float x) {
    _Float16 h = (_Float16)x;
    return __builtin_bit_cast(unsigned short, h);
}

// v_dot2_f32_f16: c += a0*b0 + a1*b1 (fp32 accumulate)
static __device__ __forceinline__ float dot2(unsigned a, unsigned y, float c) {
    union U { unsigned u; half2v h; };
    U ua; ua.u = a;
    U uy; uy.u = y;
    return __builtin_amdgcn_fdot2(ua.h, uy.h, c, false);
}

// Kernel 1: W = sigmoid(icl) * hard-concrete gate -> f16 [512][64];
// assignments fp32 -> f16 [50000][64]; zero d_out.
__global__ __launch_bounds__(256) void prep_kernel(
    const float* __restrict__ assign,
    const float* __restrict__ icl,
    const float* __restrict__ la,
    unsigned short* __restrict__ Wh,
    unsigned short* __restrict__ Ah,
    float* __restrict__ out)
{
    int tid = blockIdx.x * blockDim.x + threadIdx.x;
    int nth = gridDim.x * blockDim.x;
    if (tid == 0) out[0] = 0.0f;

    for (int i = tid; i < N_REL * N_C * N_C; i += nth) {
        float w = 1.0f / (1.0f + __expf(-icl[i]));
        float g = 1.0f / (1.0f + __expf(-la[i])) * 1.2f - 0.1f;
        g = fminf(fmaxf(g, 0.0f), 1.0f);
        Wh[i] = f2h_bits(w * g);
    }

    const float4* a4 = (const float4*)assign;
    ushort4* o4 = (ushort4*)Ah;
    int n4 = N_NODES * N_C / 4;
    for (int i = tid; i < n4; i += nth) {
        float4 v = a4[i];
        ushort4 o;
        o.x = f2h_bits(v.x); o.y = f2h_bits(v.y);
        o.z = f2h_bits(v.z); o.w = f2h_bits(v.w);
        o4[i] = o;
    }
}

// Kernel 2: Y[n][r*64+i] = sum_k A[n][k] * W_r[i][k]  (f16 MFMA GEMM).
// One wave per 16 node-rows; LDS repack epilogue -> coalesced 16B stores.
__global__ __launch_bounds__(256) void ygemm_kernel(
    const unsigned short* __restrict__ A,
    const unsigned short* __restrict__ W,   // [512][64] row-major
    unsigned short* __restrict__ Y)
{
    __shared__ __align__(16) unsigned short lds[4][16 * 136];
    int wid  = threadIdx.x >> 6;
    int wave = blockIdx.x * 4 + wid;
    int lane = threadIdx.x & 63;
    if (wave >= N_NODES / 16) return;   // no __syncthreads in this kernel
    int r16 = lane & 15, quad = lane >> 4;

    const unsigned short* arow = A + (wave * 16 + r16) * N_C + quad * 8;
    half8 a0 = *(const half8*)(arow);
    half8 a1 = *(const half8*)(arow + 32);
    unsigned short* myl = lds[wid];

    for (int c = 0; c < 4; ++c) {        // 4 chunks of 128 cols
        #pragma unroll
        for (int t = 0; t < 8; ++t) {
            int col = (c * 8 + t) * 16 + r16;
            const unsigned short* brow = W + col * N_C + quad * 8;
            half8 b0 = *(const half8*)(brow);
            half8 b1 = *(const half8*)(brow + 32);
            floatx4 acc = {0.0f, 0.0f, 0.0f, 0.0f};
            acc = __builtin_amdgcn_mfma_f32_16x16x32_f16(a0, b0, acc, 0, 0, 0);
            acc = __builtin_amdgcn_mfma_f32_16x16x32_f16(a1, b1, acc, 0, 0, 0);
            #pragma unroll
            for (int reg = 0; reg < 4; ++reg) {
                int row = quad * 4 + reg;
                myl[row * 136 + t * 16 + r16] = f2h_bits(acc[reg]);
            }
        }
        __asm__ volatile("s_waitcnt lgkmcnt(0)" ::: "memory");
        #pragma unroll
        for (int u = 0; u < 4; ++u) {
            int unit = u * 64 + lane;        // 0..255
            int row = unit >> 4, off = unit & 15;
            uint4 v = *(const uint4*)(myl + row * 136 + off * 8);
            *(uint4*)(Y + (wave * 16 + row) * NCOL + c * 128 + off * 8) = v;
        }
        __asm__ volatile("s_waitcnt lgkmcnt(0)" ::: "memory");
    }
}

// 4 edges per group, all loads issued up-front for MLP.
static __device__ __forceinline__ float edge4(
    const unsigned short* __restrict__ A,
    const unsigned short* __restrict__ Y,
    const float* bias_s,
    const int* __restrict__ eidx, const int* __restrict__ etyp,
    float sign, int group, int l)
{
    int s[4], d[4], r[4];
    #pragma unroll
    for (int j = 0; j < 4; ++j) {
        int e = group + j * GROUPS;
        s[j] = eidx[e];
        d[j] = eidx[E_EDGES + e];
        r[j] = etyp[e];
    }
    uint4 a0[4], a1[4], y0[4], y1[4];
    #pragma unroll
    for (int j = 0; j < 4; ++j) {
        const uint4* ap = (const uint4*)(A + s[j] * N_C + l * 16);
        const uint4* yp = (const uint4*)(Y + (size_t)d[j] * NCOL + r[j] * N_C + l * 16);
        a0[j] = ap[0]; a1[j] = ap[1];
        y0[j] = yp[0]; y1[j] = yp[1];
    }
    float acc = 0.0f;
    #pragma unroll
    for (int j = 0; j < 4; ++j) {
        float d0 = 0.0f, d1 = 0.0f;
        d0 = dot2(a0[j].x, y0[j].x, d0); d1 = dot2(a1[j].x, y1[j].x, d1);
        d0 = dot2(a0[j].y, y0[j].y, d0); d1 = dot2(a1[j].y, y1[j].y, d1);
        d0 = dot2(a0[j].z, y0[j].z, d0); d1 = dot2(a1[j].z, y1[j].z, d1);
        d0 = dot2(a0[j].w, y0[j].w, d0); d1 = dot2(a1[j].w, y1[j].w, d1);
        float dot = d0 + d1;
        dot += __shfl_xor(dot, 1);
        dot += __shfl_xor(dot, 2);
        if (l == 0) {
            float x = sign * (dot + bias_s[r[j]]);
            acc += fmaxf(x, 0.0f) + __logf(1.0f + __expf(-fabsf(x)));
        }
    }
    return acc;
}

__global__ __launch_bounds__(256, 4) void edge_kernel(
    const unsigned short* __restrict__ A,
    const unsigned short* __restrict__ Y,
    const float* __restrict__ absent_bias,
    const int* __restrict__ ei, const int* __restrict__ et,
    const int* __restrict__ nei, const int* __restrict__ net,
    float* __restrict__ out)
{
    __shared__ float bias_s[N_REL];
    if (threadIdx.x < N_REL) bias_s[threadIdx.x] = absent_bias[threadIdx.x];
    __syncthreads();

    int tid = blockIdx.x * blockDim.x + threadIdx.x;
    int l = tid & 3;
    int group = tid >> 2;

    float acc = 0.0f;
    if (group < GROUPS) {
        acc += edge4(A, Y, bias_s, ei,  et,  -1.0f, group, l);  // pos
        acc += edge4(A, Y, bias_s, nei, net,  1.0f, group, l);  // neg
    }

    acc += __shfl_xor(acc, 1);
    acc += __shfl_xor(acc, 2);
    acc += __shfl_xor(acc, 4);
    acc += __shfl_xor(acc, 8);
    acc += __shfl_xor(acc, 16);
    acc += __shfl_xor(acc, 32);
    __shared__ float red[4];
    if ((threadIdx.x & 63) == 0) red[threadIdx.x >> 6] = acc;
    __syncthreads();
    if (threadIdx.x == 0)
        atomicAdd(out, (red[0] + red[1] + red[2] + red[3]) * (1.0f / (float)E_EDGES));
}

extern "C" void kernel_launch(void* const* d_in, const int* in_sizes, int n_in,
                              void* d_out, int out_size, void* d_ws, size_t ws_size,
                              hipStream_t stream) {
    const float* assign = (const float*)d_in[0];
    const float* icl    = (const float*)d_in[1];
    const float* la     = (const float*)d_in[2];
    const float* ab     = (const float*)d_in[3];
    const int*   ei     = (const int*)d_in[4];
    const int*   et     = (const int*)d_in[5];
    const int*   nei    = (const int*)d_in[6];
    const int*   net    = (const int*)d_in[7];
    float* out = (float*)d_out;

    // workspace: Wh 64KB | Ah 6.4MB | Y 51.2MB
    unsigned short* Wh = (unsigned short*)d_ws;
    unsigned short* Ah = (unsigned short*)((char*)d_ws + 65536);
    unsigned short* Y  = (unsigned short*)((char*)d_ws + 65536 + N_NODES * N_C * 2);

    prep_kernel<<<1024, 256, 0, stream>>>(assign, icl, la, Wh, Ah, out);
    ygemm_kernel<<<(N_NODES / 16 + 3) / 4, 256, 0, stream>>>(Ah, Wh, Y);
    edge_kernel<<<(GROUPS * 4 + 255) / 256, 256, 0, stream>>>(Ah, Y, ab, ei, et, nei, net, out);
}

// Round 4
// 191.568 us; speedup vs baseline: 1.0760x; 1.0066x over previous
//
#include <hip/hip_runtime.h>
#include <hip/hip_bf16.h>
#include <math.h>

#define E_EDGES 1000000
#define N_NODES 50000
#define N_C     64
#define N_REL   8
#define NCOL    512     // N_REL * N_C (bytes per Y row in fp8)
#define GROUPS  250000  // 4 lanes/group, 4 pos + 4 neg edges per group

typedef _Float16 half2v __attribute__((ext_vector_type(2)));
typedef _Float16 half8  __attribute__((ext_vector_type(8)));
typedef __attribute__((ext_vector_type(4))) float floatx4;
typedef __attribute__((ext_vector_type(2))) float floatx2;

static __device__ __forceinline__ unsigned short f2h_bits(float x) {
    _Float16 h = (_Float16)x;
    return __builtin_bit_cast(unsigned short, h);
}

// pack 4 fp32 -> 4 fp8 e4m3 (RNE) in one uint
static __device__ __forceinline__ unsigned pk4_fp8(float a, float b, float c, float d) {
    unsigned w = 0;
    w = __builtin_amdgcn_cvt_pk_fp8_f32(a, b, w, false);
    w = __builtin_amdgcn_cvt_pk_fp8_f32(c, d, w, true);
    return w;
}

// dot of 4 fp8 pairs packed in words a,y (one uint each), fp32 accumulate
static __device__ __forceinline__ float dot4_fp8(unsigned a, unsigned y, float acc) {
    floatx2 a0 = __builtin_amdgcn_cvt_pk_f32_fp8((int)a, false);
    floatx2 a1 = __builtin_amdgcn_cvt_pk_f32_fp8((int)a, true);
    floatx2 y0 = __builtin_amdgcn_cvt_pk_f32_fp8((int)y, false);
    floatx2 y1 = __builtin_amdgcn_cvt_pk_f32_fp8((int)y, true);
    acc = fmaf(a0.x, y0.x, acc);
    acc = fmaf(a0.y, y0.y, acc);
    acc = fmaf(a1.x, y1.x, acc);
    acc = fmaf(a1.y, y1.y, acc);
    return acc;
}

// Kernel 1: W -> f16 [512][64]; assignments -> f16 (for MFMA) AND fp8 (for
// edge gathers); zero d_out.
__global__ __launch_bounds__(256) void prep_kernel(
    const float* __restrict__ assign,
    const float* __restrict__ icl,
    const float* __restrict__ la,
    unsigned short* __restrict__ Wh,
    unsigned short* __restrict__ Ah,
    unsigned char*  __restrict__ A8,
    float* __restrict__ out)
{
    int tid = blockIdx.x * blockDim.x + threadIdx.x;
    int nth = gridDim.x * blockDim.x;
    if (tid == 0) out[0] = 0.0f;

    for (int i = tid; i < N_REL * N_C * N_C; i += nth) {
        float w = 1.0f / (1.0f + __expf(-icl[i]));
        float g = 1.0f / (1.0f + __expf(-la[i])) * 1.2f - 0.1f;
        g = fminf(fmaxf(g, 0.0f), 1.0f);
        Wh[i] = f2h_bits(w * g);
    }

    const float4* a4 = (const float4*)assign;
    int n8 = N_NODES * N_C / 8;
    for (int i = tid; i < n8; i += nth) {
        float4 v0 = a4[2 * i], v1 = a4[2 * i + 1];
        ushort4 h0, h1;
        h0.x = f2h_bits(v0.x); h0.y = f2h_bits(v0.y);
        h0.z = f2h_bits(v0.z); h0.w = f2h_bits(v0.w);
        h1.x = f2h_bits(v1.x); h1.y = f2h_bits(v1.y);
        h1.z = f2h_bits(v1.z); h1.w = f2h_bits(v1.w);
        *(ushort4*)(Ah + 8 * i)     = h0;
        *(ushort4*)(Ah + 8 * i + 4) = h1;
        uint2 p;
        p.x = pk4_fp8(v0.x, v0.y, v0.z, v0.w);
        p.y = pk4_fp8(v1.x, v1.y, v1.z, v1.w);
        ((uint2*)A8)[i] = p;
    }
}

// Kernel 2: Y[n][r*64+i] = sum_k A[n][k] * W_r[i][k]  (f16 MFMA GEMM).
// Epilogue: acc -> f16 -> LDS repack -> read coalesced -> fp8 -> 8B stores.
__global__ __launch_bounds__(256) void ygemm_kernel(
    const unsigned short* __restrict__ A,
    const unsigned short* __restrict__ W,   // [512][64] row-major
    unsigned char* __restrict__ Y8)
{
    __shared__ __align__(16) unsigned short lds[4][16 * 136];
    int wid  = threadIdx.x >> 6;
    int wave = blockIdx.x * 4 + wid;
    int lane = threadIdx.x & 63;
    if (wave >= N_NODES / 16) return;   // no __syncthreads in this kernel
    int r16 = lane & 15, quad = lane >> 4;

    const unsigned short* arow = A + (wave * 16 + r16) * N_C + quad * 8;
    half8 a0 = *(const half8*)(arow);
    half8 a1 = *(const half8*)(arow + 32);
    unsigned short* myl = lds[wid];

    for (int c = 0; c < 4; ++c) {        // 4 chunks of 128 cols
        #pragma unroll
        for (int t = 0; t < 8; ++t) {
            int col = (c * 8 + t) * 16 + r16;
            const unsigned short* brow = W + col * N_C + quad * 8;
            half8 b0 = *(const half8*)(brow);
            half8 b1 = *(const half8*)(brow + 32);
            floatx4 acc = {0.0f, 0.0f, 0.0f, 0.0f};
            acc = __builtin_amdgcn_mfma_f32_16x16x32_f16(a0, b0, acc, 0, 0, 0);
            acc = __builtin_amdgcn_mfma_f32_16x16x32_f16(a1, b1, acc, 0, 0, 0);
            #pragma unroll
            for (int reg = 0; reg < 4; ++reg) {
                int row = quad * 4 + reg;
                myl[row * 136 + t * 16 + r16] = f2h_bits(acc[reg]);
            }
        }
        __asm__ volatile("s_waitcnt lgkmcnt(0)" ::: "memory");
        // read 8 f16 per lane, convert to 8 fp8, store 8B coalesced
        #pragma unroll
        for (int u = 0; u < 4; ++u) {
            int unit = u * 64 + lane;        // 0..255
            int row = unit >> 4, off = unit & 15;   // off = 8-col group
            uint4 v = *(const uint4*)(myl + row * 136 + off * 8);
            half2v p0 = __builtin_bit_cast(half2v, v.x);
            half2v p1 = __builtin_bit_cast(half2v, v.y);
            half2v p2 = __builtin_bit_cast(half2v, v.z);
            half2v p3 = __builtin_bit_cast(half2v, v.w);
            uint2 o;
            o.x = pk4_fp8((float)p0[0], (float)p0[1], (float)p1[0], (float)p1[1]);
            o.y = pk4_fp8((float)p2[0], (float)p2[1], (float)p3[0], (float)p3[1]);
            *(uint2*)(Y8 + (size_t)(wave * 16 + row) * NCOL + c * 128 + off * 8) = o;
        }
        __asm__ volatile("s_waitcnt lgkmcnt(0)" ::: "memory");
    }
}

// 4 edges per group (4 lanes/edge); fp8 rows: 1 uint4 per lane per row.
static __device__ __forceinline__ float edge4(
    const unsigned char* __restrict__ A8,
    const unsigned char* __restrict__ Y8,
    const float* bias_s,
    const int* __restrict__ eidx, const int* __restrict__ etyp,
    float sign, int group, int l)
{
    int s[4], d[4], r[4];
    #pragma unroll
    for (int j = 0; j < 4; ++j) {
        int e = group + j * GROUPS;
        s[j] = eidx[e];
        d[j] = eidx[E_EDGES + e];
        r[j] = etyp[e];
    }
    uint4 av[4], yv[4];
    #pragma unroll
    for (int j = 0; j < 4; ++j) {
        av[j] = *(const uint4*)(A8 + (size_t)s[j] * N_C + l * 16);
        yv[j] = *(const uint4*)(Y8 + (size_t)d[j] * NCOL + r[j] * N_C + l * 16);
    }
    float acc = 0.0f;
    #pragma unroll
    for (int j = 0; j < 4; ++j) {
        float dot = 0.0f;
        dot = dot4_fp8(av[j].x, yv[j].x, dot);
        dot = dot4_fp8(av[j].y, yv[j].y, dot);
        dot = dot4_fp8(av[j].z, yv[j].z, dot);
        dot = dot4_fp8(av[j].w, yv[j].w, dot);
        dot += __shfl_xor(dot, 1);
        dot += __shfl_xor(dot, 2);
        if (l == 0) {
            float x = sign * (dot + bias_s[r[j]]);
            acc += fmaxf(x, 0.0f) + __logf(1.0f + __expf(-fabsf(x)));
        }
    }
    return acc;
}

__global__ __launch_bounds__(256, 4) void edge_kernel(
    const unsigned char* __restrict__ A8,
    const unsigned char* __restrict__ Y8,
    const float* __restrict__ absent_bias,
    const int* __restrict__ ei, const int* __restrict__ et,
    const int* __restrict__ nei, const int* __restrict__ net,
    float* __restrict__ out)
{
    __shared__ float bias_s[N_REL];
    if (threadIdx.x < N_REL) bias_s[threadIdx.x] = absent_bias[threadIdx.x];
    __syncthreads();

    int tid = blockIdx.x * blockDim.x + threadIdx.x;
    int l = tid & 3;
    int group = tid >> 2;

    float acc = 0.0f;
    if (group < GROUPS) {
        acc += edge4(A8, Y8, bias_s, ei,  et,  -1.0f, group, l);  // pos
        acc += edge4(A8, Y8, bias_s, nei, net,  1.0f, group, l);  // neg
    }

    acc += __shfl_xor(acc, 1);
    acc += __shfl_xor(acc, 2);
    acc += __shfl_xor(acc, 4);
    acc += __shfl_xor(acc, 8);
    acc += __shfl_xor(acc, 16);
    acc += __shfl_xor(acc, 32);
    __shared__ float red[4];
    if ((threadIdx.x & 63) == 0) red[threadIdx.x >> 6] = acc;
    __syncthreads();
    if (threadIdx.x == 0)
        atomicAdd(out, (red[0] + red[1] + red[2] + red[3]) * (1.0f / (float)E_EDGES));
}

extern "C" void kernel_launch(void* const* d_in, const int* in_sizes, int n_in,
                              void* d_out, int out_size, void* d_ws, size_t ws_size,
                              hipStream_t stream) {
    const float* assign = (const float*)d_in[0];
    const float* icl    = (const float*)d_in[1];
    const float* la     = (const float*)d_in[2];
    const float* ab     = (const float*)d_in[3];
    const int*   ei     = (const int*)d_in[4];
    const int*   et     = (const int*)d_in[5];
    const int*   nei    = (const int*)d_in[6];
    const int*   net    = (const int*)d_in[7];
    float* out = (float*)d_out;

    // workspace: Wh 64KB | Ah(f16) 6.4MB | A8(fp8) 3.2MB | Y8(fp8) 25.6MB
    char* base = (char*)d_ws;
    unsigned short* Wh = (unsigned short*)base;
    unsigned short* Ah = (unsigned short*)(base + 65536);
    unsigned char*  A8 = (unsigned char*)(base + 65536 + (size_t)N_NODES * N_C * 2);
    unsigned char*  Y8 = (unsigned char*)(base + 65536 + (size_t)N_NODES * N_C * 3);

    prep_kernel<<<1024, 256, 0, stream>>>(assign, icl, la, Wh, Ah, A8, out);
    ygemm_kernel<<<(N_NODES / 16 + 3) / 4, 256, 0, stream>>>(Ah, Wh, Y8);
    edge_kernel<<<(GROUPS * 4 + 255) / 256, 256, 0, stream>>>(A8, Y8, ab, ei, et, nei, net, out);
}